// Round 19
// baseline (37.246 us; speedup 1.0000x reference)
//
#include <hip/hip_runtime.h>
#include <hip/hip_fp16.h>

// Box-log-edge, v20: v13 structure with 64x32 tiles (vertical-halo amortized:
// 42 Phase-A rows / 32 output rows = 1.31x vs v13's 1.63x), 1-wave blocks,
// register-ring Phase A (12 slots, compile-time indices), 4-strip Phase B.
// Phase A (38 lanes): float2 loads, rolling 6-row sums over 42 padded rows ->
//   S6[0..36] (+0.06) and full11[0..31] (+0.11), fp16. bot6[r] == S6[r+5].
// Phase B (64 lanes x 4 strips of 8 px): 20-half loads, register sliding
//   windows, log-domain ratio + L2 norm, float4 stores.

#define N   512
#define SH  80            // LDS row stride in halfs (160B)
#define LN2 0.69314718056f

typedef __fp16 h2  __attribute__((ext_vector_type(2)));
typedef __fp16 h4v __attribute__((ext_vector_type(4)));
typedef __fp16 h8v __attribute__((ext_vector_type(8)));

__device__ __forceinline__ float2 f2add(float2 a, float2 b){ return make_float2(a.x+b.x, a.y+b.y); }
__device__ __forceinline__ float2 f2sub(float2 a, float2 b){ return make_float2(a.x-b.x, a.y-b.y); }

// Load halfs [base .. base+19] into f32 t[0..19], registers only.
__device__ __forceinline__ void load20(const __half* __restrict__ arr, int base, float* __restrict__ t) {
    h8v a = *(const h8v*)(arr + base);
    h8v b = *(const h8v*)(arr + base + 8);
    h4v c = *(const h4v*)(arr + base + 16);
    #pragma unroll
    for (int j = 0; j < 8; ++j) t[j]      = (float)a[j];
    #pragma unroll
    for (int j = 0; j < 8; ++j) t[8 + j]  = (float)b[j];
    #pragma unroll
    for (int j = 0; j < 4; ++j) t[16 + j] = (float)c[j];
}

__global__ __launch_bounds__(64, 4) void boxlog_kernel(
    const float* __restrict__ x, float* __restrict__ out)
{
    __shared__ __align__(16) __half S6A [37*SH];   // S6[r] = padded rows r..r+5 (+0.06)
    __shared__ __align__(16) __half fulA[32*SH];   // full11[r] = rows r..r+10 (+0.11)

    const int lane = threadIdx.x;
    // XCD-aware swizzle over 8192 blocks: each XCD gets 8 contiguous images
    const int wg  = blockIdx.x;
    const int sw  = (wg & 7) * 1024 + (wg >> 3);
    const int bz  = sw >> 7;          // image 0..63
    const int rem = sw & 127;
    const int by  = rem >> 3;         // 0..15 (32-row tiles)
    const int bx  = rem & 7;          // 0..7  (64-col tiles)
    const int X0 = bx * 64, Y0 = by * 32;
    const float* __restrict__ xb   = x   + (size_t)bz * ((size_t)N * N);
    float* __restrict__       outb = out + (size_t)bz * ((size_t)N * N);

    // ---------------- Phase A: rolling S6 + full11 (fp16 to LDS) ------------
    // 38 lanes x 2 cols (local halfs 2l..2l+1 <-> global X0-6+2l), 42 padded
    // rows streamed through a 12-slot register ring (indices all literal).
    if (lane < 38) {
        const int gc = X0 - 6 + 2 * lane;  // even -> 8B-aligned float2

        auto body = [&](auto loadrow) {
            float2 t[12];
            #pragma unroll
            for (int j = 0; j < 11; ++j) t[j] = loadrow(j);
            float2 lo = f2add(f2add(f2add(t[0],t[1]), f2add(t[2],t[3])), f2add(t[4],t[5]));
            float2 hi = f2add(f2add(f2add(t[5],t[6]), f2add(t[7],t[8])), f2add(t[9],t[10]));
            {
                float2 fv = f2sub(f2add(lo, hi), t[5]);
                *(h2*)&S6A [2 * lane] = __builtin_amdgcn_cvt_pkrtz(lo.x + 0.06f, lo.y + 0.06f);
                *(h2*)&fulA[2 * lane] = __builtin_amdgcn_cvt_pkrtz(fv.x + 0.06f + 0.05f, fv.y + 0.11f);
            }
            #pragma unroll
            for (int k = 1; k < 37; ++k) {
                if (k < 32) t[(k + 10) % 12] = loadrow(k + 10);  // row k+10 (<=41)
                lo = f2sub(f2add(lo, t[(k + 5) % 12]), t[(k + 11) % 12]);  // (k-1)%12
                *(h2*)&S6A[k * SH + 2 * lane] = __builtin_amdgcn_cvt_pkrtz(lo.x + 0.06f, lo.y + 0.06f);
                if (k < 32) {
                    hi = f2sub(f2add(hi, t[(k + 10) % 12]), t[(k + 4) % 12]);
                    float2 fv = f2sub(f2add(lo, hi), t[(k + 5) % 12]);
                    *(h2*)&fulA[k * SH + 2 * lane] = __builtin_amdgcn_cvt_pkrtz(fv.x + 0.11f, fv.y + 0.11f);
                }
            }
        };

        if (by >= 1 && by <= 14 && bx >= 1 && bx <= 6) {
            body([&](int j) {
                return *(const float2*)(xb + (size_t)(Y0 - 5 + j) * N + gc);
            });
        } else {
            const bool vec = (gc >= 0) && (gc <= N - 2);
            body([&](int j) {
                int gr = Y0 - 5 + j;
                gr = gr < 0 ? -gr : (gr > N-1 ? 2*(N-1) - gr : gr);
                const float* rowp = xb + (size_t)gr * N;
                if (vec) return *(const float2*)(rowp + gc);
                int c0 = gc, c1 = gc + 1;
                c0 = c0 < 0 ? -c0 : (c0 > N-1 ? 2*(N-1) - c0 : c0);
                c1 = c1 < 0 ? -c1 : (c1 > N-1 ? 2*(N-1) - c1 : c1);
                return make_float2(rowp[c0], rowp[c1]);
            });
        }
    }
    __syncthreads();   // single-wave block: in-wave waitcnt only

    // ---------------- Phase B: 4 independent 8-px sliding-window strips ------
    // t[i] <-> local col 8*tx + i ; out col o = 8*tx+p uses window t[p+1..p+11]
    const int tx = lane & 7;      // 8 strips of 8 px
    const int ty = lane >> 3;     // 0..7 -> rows ty, ty+8, ty+16, ty+24
    #pragma unroll
    for (int s = 0; s < 4; ++s) {
        const int row  = ty + 8 * s;
        const int base = row * SH + 8 * tx;

        float gy1[8], ly[8];
        {   // top6 = S6[row] -> gy1 windows (11-wide)
            float t[20];
            load20(S6A, base, t);
            float g = ((t[1]+t[2])+(t[3]+t[4]))+((t[5]+t[6])+(t[7]+t[8]))+((t[9]+t[10])+t[11]);
            gy1[0] = g;
            #pragma unroll
            for (int p = 1; p < 8; ++p) { g += t[p+11] - t[p]; gy1[p] = g; }
        }
        {   // bot6 = S6[row+5] -> gy2 windows, fold into log ratio
            float t[20];
            load20(S6A, base + 5*SH, t);
            float g = ((t[1]+t[2])+(t[3]+t[4]))+((t[5]+t[6])+(t[7]+t[8]))+((t[9]+t[10])+t[11]);
            ly[0] = __builtin_amdgcn_logf(gy1[0]) - __builtin_amdgcn_logf(g);
            #pragma unroll
            for (int p = 1; p < 8; ++p) {
                g += t[p+11] - t[p];
                ly[p] = __builtin_amdgcn_logf(gy1[p]) - __builtin_amdgcn_logf(g);
            }
        }
        {   // full11 -> gx window pair (6-wide), combine + store
            float t[20];
            load20(fulA, base, t);
            float g1 = ((t[1]+t[2])+(t[3]+t[4]))+(t[5]+t[6]);
            float g2 = ((t[6]+t[7])+(t[8]+t[9]))+(t[10]+t[11]);
            float r8[8];
            #pragma unroll
            for (int p = 0; p < 8; ++p) {
                if (p) {
                    g1 += t[p+6]  - t[p];
                    g2 += t[p+11] - t[p+5];
                }
                float lx = __builtin_amdgcn_logf(g1) - __builtin_amdgcn_logf(g2);
                r8[p] = LN2 * __builtin_amdgcn_sqrtf(lx*lx + ly[p]*ly[p]);
            }
            float* op = outb + (size_t)(Y0 + row) * N + X0 + tx * 8;
            *(float4*)op       = make_float4(r8[0], r8[1], r8[2], r8[3]);
            *(float4*)(op + 4) = make_float4(r8[4], r8[5], r8[6], r8[7]);
        }
    }
}

extern "C" void kernel_launch(void* const* d_in, const int* in_sizes, int n_in,
                              void* d_out, int out_size, void* d_ws, size_t ws_size,
                              hipStream_t stream) {
    const float* x = (const float*)d_in[0];  // (64,1,512,512) fp32
    float* out = (float*)d_out;              // (64,1,512,512) fp32
    dim3 grid(8 * 16 * 64);                  // 64x32 tiles, swizzled in-kernel
    dim3 block(64);
    boxlog_kernel<<<grid, block, 0, stream>>>(x, out);
}

// Round 20
// 33.346 us; speedup vs baseline: 1.1170x; 1.1170x over previous
//
#include <hip/hip_runtime.h>
#include <hip/hip_fp16.h>

// Box-log-edge, FINAL (= v13, empirical best 33.3us over 19 rounds).
// 1-wave workgroups: block = 64 thr, tile 64x16. Producer wave == consumer
// wave, so __syncthreads degenerates to in-wave waitcnt; no inter-wave
// coupling. fp16 LDS 5.9KB/block.
// Phase A (38 lanes): float2 loads, rolling 6-row sums over 26 padded rows ->
//   S6[0..20] (+0.06) and full11[0..15] (+0.11), fp16. bot6[r] == S6[r+5].
// Phase B (64 lanes x 2 strips of 8 px): 20-half loads, register sliding
//   windows, log-domain ratio + L2 norm, float4 stores.
// Explored and rejected (all >= 33.3us): 256-thr tiles (barrier coupling),
// f32 LDS (DS-pipe + occupancy payback), packed f32, shared-log algebra,
// 16-px strips (ILP loss), 64x32 ring (VALU payback), load hoist, 2-wave
// no-barrier packing. Regime: balanced VALU+DS+latency floor, ~2x the pure
// memory floor (~16us: 65.5MB writes + ~34MB L3-miss reads).

#define N   512
#define SH  80            // LDS row stride in halfs (160B)
#define LN2 0.69314718056f

typedef __fp16 h2  __attribute__((ext_vector_type(2)));
typedef __fp16 h4v __attribute__((ext_vector_type(4)));
typedef __fp16 h8v __attribute__((ext_vector_type(8)));

__device__ __forceinline__ float2 f2add(float2 a, float2 b){ return make_float2(a.x+b.x, a.y+b.y); }
__device__ __forceinline__ float2 f2sub(float2 a, float2 b){ return make_float2(a.x-b.x, a.y-b.y); }

// Load halfs [base .. base+19] into f32 t[0..19], registers only.
__device__ __forceinline__ void load20(const __half* __restrict__ arr, int base, float* __restrict__ t) {
    h8v a = *(const h8v*)(arr + base);
    h8v b = *(const h8v*)(arr + base + 8);
    h4v c = *(const h4v*)(arr + base + 16);
    #pragma unroll
    for (int j = 0; j < 8; ++j) t[j]      = (float)a[j];
    #pragma unroll
    for (int j = 0; j < 8; ++j) t[8 + j]  = (float)b[j];
    #pragma unroll
    for (int j = 0; j < 4; ++j) t[16 + j] = (float)c[j];
}

__global__ __launch_bounds__(64, 6) void boxlog_kernel(
    const float* __restrict__ x, float* __restrict__ out)
{
    __shared__ __align__(16) __half S6A [21*SH];   // S6[r] = padded rows r..r+5 (+0.06)
    __shared__ __align__(16) __half fulA[16*SH];   // full11[r] = rows r..r+10 (+0.11)

    const int lane = threadIdx.x;
    // XCD-aware swizzle over 16384 blocks: each XCD gets 8 contiguous images
    const int wg  = blockIdx.x;
    const int sw  = (wg & 7) * 2048 + (wg >> 3);
    const int bz  = sw >> 8;          // image 0..63
    const int rem = sw & 255;
    const int by  = rem >> 3;         // 0..31 (16-row tiles)
    const int bx  = rem & 7;          // 0..7  (64-col tiles)
    const int X0 = bx * 64, Y0 = by * 16;
    const float* __restrict__ xb   = x   + (size_t)bz * ((size_t)N * N);
    float* __restrict__       outb = out + (size_t)bz * ((size_t)N * N);

    // ---------------- Phase A: rolling S6 + full11 (fp16 to LDS) ------------
    // 38 lanes x 2 cols (local halfs 2l..2l+1 <-> global X0-6+2l), 26 padded rows.
    if (lane < 38) {
        const int gc = X0 - 6 + 2 * lane;  // even -> 8B-aligned float2

        auto body = [&](auto loadrow) {
            float2 t[26];
            #pragma unroll
            for (int j = 0; j < 11; ++j) t[j] = loadrow(j);
            float2 lo = f2add(f2add(f2add(t[0],t[1]), f2add(t[2],t[3])), f2add(t[4],t[5]));
            float2 hi = f2add(f2add(f2add(t[5],t[6]), f2add(t[7],t[8])), f2add(t[9],t[10]));
            {
                float2 fu = f2sub(f2add(lo, hi), t[5]);
                *(h2*)&S6A [2 * lane] = __builtin_amdgcn_cvt_pkrtz(lo.x + 0.06f, lo.y + 0.06f);
                *(h2*)&fulA[2 * lane] = __builtin_amdgcn_cvt_pkrtz(fu.x + 0.11f, fu.y + 0.11f);
            }
            #pragma unroll
            for (int k = 1; k < 21; ++k) {
                if (k < 16) t[k+10] = loadrow(k + 10);
                lo = f2sub(f2add(lo, t[k+5]), t[k-1]);
                *(h2*)&S6A[k * SH + 2 * lane] = __builtin_amdgcn_cvt_pkrtz(lo.x + 0.06f, lo.y + 0.06f);
                if (k < 16) {
                    hi = f2sub(f2add(hi, t[k+10]), t[k+4]);
                    float2 fu = f2sub(f2add(lo, hi), t[k+5]);
                    *(h2*)&fulA[k * SH + 2 * lane] = __builtin_amdgcn_cvt_pkrtz(fu.x + 0.11f, fu.y + 0.11f);
                }
            }
        };

        if (by >= 1 && by <= 30 && bx >= 1 && bx <= 6) {
            body([&](int j) {
                return *(const float2*)(xb + (size_t)(Y0 - 5 + j) * N + gc);
            });
        } else {
            const bool vec = (gc >= 0) && (gc <= N - 2);
            body([&](int j) {
                int gr = Y0 - 5 + j;
                gr = gr < 0 ? -gr : (gr > N-1 ? 2*(N-1) - gr : gr);
                const float* rowp = xb + (size_t)gr * N;
                if (vec) return *(const float2*)(rowp + gc);
                int c0 = gc, c1 = gc + 1;
                c0 = c0 < 0 ? -c0 : (c0 > N-1 ? 2*(N-1) - c0 : c0);
                c1 = c1 < 0 ? -c1 : (c1 > N-1 ? 2*(N-1) - c1 : c1);
                return make_float2(rowp[c0], rowp[c1]);
            });
        }
    }
    __syncthreads();   // single-wave block: compiles to in-wave waitcnt, no coupling

    // ---------------- Phase B: 2 independent 8-px sliding-window strips ------
    // t[i] <-> local col 8*tx + i ; out col o = 8*tx+p uses window t[p+1..p+11]
    const int tx = lane & 7;      // 8 strips of 8 px
    const int ty = lane >> 3;     // 0..7 -> rows ty and ty+8
    #pragma unroll
    for (int s = 0; s < 2; ++s) {
        const int row  = ty + 8 * s;
        const int base = row * SH + 8 * tx;

        float gy1[8], ly[8];
        {   // top6 = S6[row] -> gy1 windows (11-wide)
            float t[20];
            load20(S6A, base, t);
            float g = ((t[1]+t[2])+(t[3]+t[4]))+((t[5]+t[6])+(t[7]+t[8]))+((t[9]+t[10])+t[11]);
            gy1[0] = g;
            #pragma unroll
            for (int p = 1; p < 8; ++p) { g += t[p+11] - t[p]; gy1[p] = g; }
        }
        {   // bot6 = S6[row+5] -> gy2 windows, fold into log ratio
            float t[20];
            load20(S6A, base + 5*SH, t);
            float g = ((t[1]+t[2])+(t[3]+t[4]))+((t[5]+t[6])+(t[7]+t[8]))+((t[9]+t[10])+t[11]);
            ly[0] = __builtin_amdgcn_logf(gy1[0]) - __builtin_amdgcn_logf(g);
            #pragma unroll
            for (int p = 1; p < 8; ++p) {
                g += t[p+11] - t[p];
                ly[p] = __builtin_amdgcn_logf(gy1[p]) - __builtin_amdgcn_logf(g);
            }
        }
        {   // full11 -> gx window pair (6-wide), combine + store
            float t[20];
            load20(fulA, base, t);
            float g1 = ((t[1]+t[2])+(t[3]+t[4]))+(t[5]+t[6]);
            float g2 = ((t[6]+t[7])+(t[8]+t[9]))+(t[10]+t[11]);
            float r8[8];
            #pragma unroll
            for (int p = 0; p < 8; ++p) {
                if (p) {
                    g1 += t[p+6]  - t[p];
                    g2 += t[p+11] - t[p+5];
                }
                float lx = __builtin_amdgcn_logf(g1) - __builtin_amdgcn_logf(g2);
                r8[p] = LN2 * __builtin_amdgcn_sqrtf(lx*lx + ly[p]*ly[p]);
            }
            float* op = outb + (size_t)(Y0 + row) * N + X0 + tx * 8;
            *(float4*)op       = make_float4(r8[0], r8[1], r8[2], r8[3]);
            *(float4*)(op + 4) = make_float4(r8[4], r8[5], r8[6], r8[7]);
        }
    }
}

extern "C" void kernel_launch(void* const* d_in, const int* in_sizes, int n_in,
                              void* d_out, int out_size, void* d_ws, size_t ws_size,
                              hipStream_t stream) {
    const float* x = (const float*)d_in[0];  // (64,1,512,512) fp32
    float* out = (float*)d_out;              // (64,1,512,512) fp32
    dim3 grid(8 * 32 * 64);                  // 64x16 tiles, swizzled in-kernel
    dim3 block(64);
    boxlog_kernel<<<grid, block, 0, stream>>>(x, out);
}